// Round 6
// baseline (1067.018 us; speedup 1.0000x reference)
//
#include <hip/hip_runtime.h>

constexpr int NN = 120000;
constexpr int EE = 1200000;
constexpr float EPSV = 1e-5f;
constexpr int NB_SCAN = (NN + 255) / 256;   // 469
constexpr int NCBLK   = (NN + 127) / 128;   // 938 (128 nodes per GEMM block)

// ---------------- CSR build ----------------
__global__ __launch_bounds__(256) void k_count(const int* __restrict__ dst, int* __restrict__ cnt){
  int e = blockIdx.x*256 + threadIdx.x;
  if (e < EE) atomicAdd(&cnt[dst[e]], 1);
}

__global__ __launch_bounds__(256) void k_scan1(const int* __restrict__ cnt, int* __restrict__ pre,
                                               int* __restrict__ blksum){
  __shared__ int sm[256];
  int i = blockIdx.x*256 + threadIdx.x;
  int v = (i < NN) ? cnt[i] : 0;
  sm[threadIdx.x] = v; __syncthreads();
  for (int off = 1; off < 256; off <<= 1){
    int t = (threadIdx.x >= off) ? sm[threadIdx.x - off] : 0;
    __syncthreads();
    sm[threadIdx.x] += t;
    __syncthreads();
  }
  if (i < NN) pre[i] = sm[threadIdx.x] - v;
  if (threadIdx.x == 255) blksum[blockIdx.x] = sm[255];
}

__global__ __launch_bounds__(512) void k_scan2(int* __restrict__ blksum){
  __shared__ int sm[512];
  int v = (threadIdx.x < NB_SCAN) ? blksum[threadIdx.x] : 0;
  sm[threadIdx.x] = v; __syncthreads();
  for (int off = 1; off < 512; off <<= 1){
    int t = (threadIdx.x >= off) ? sm[threadIdx.x - off] : 0;
    __syncthreads();
    sm[threadIdx.x] += t;
    __syncthreads();
  }
  if (threadIdx.x < NB_SCAN) blksum[threadIdx.x] = sm[threadIdx.x] - v;
}

__global__ __launch_bounds__(256) void k_scan3(const int* __restrict__ pre, const int* __restrict__ blksum,
                                               const int* __restrict__ cnt,
                                               int* __restrict__ row_ptr, int* __restrict__ cursor,
                                               float* __restrict__ invdeg){
  int i = blockIdx.x*256 + threadIdx.x;
  if (i < NN){
    int r = pre[i] + blksum[blockIdx.x];
    row_ptr[i] = r; cursor[i] = r;
    int c = cnt[i];
    invdeg[i] = (c > 0) ? (1.0f/(float)c) : -1.0f;
  }
}

__global__ __launch_bounds__(256) void k_fill(const int* __restrict__ src, const int* __restrict__ dst,
                                              int* __restrict__ cursor, int* __restrict__ adj){
  int e = blockIdx.x*256 + threadIdx.x;
  if (e < EE){
    int p = atomicAdd(&cursor[dst[e]], 1);
    adj[p] = src[e];
  }
}

// ---------------- Aggregation: gather by destination, 4-deep load pipeline ----------------
__global__ __launch_bounds__(256) void k_gather64(const float* __restrict__ x, const int* __restrict__ row_ptr,
                                                  const int* __restrict__ cnt, const int* __restrict__ adj,
                                                  float* __restrict__ agg){
  const int lane = threadIdx.x & 63;
  const int wave = blockIdx.x*4 + (threadIdx.x >> 6);
  const int nwav = gridDim.x*4;
  for (int n = wave; n < NN; n += nwav){
    int st = row_ptr[n], d = cnt[n];
    float a0 = 0.0f, a1 = 0.0f, a2 = 0.0f, a3 = 0.0f;
    int j = 0;
    for (; j + 3 < d; j += 4){
      int s0 = adj[st+j], s1 = adj[st+j+1], s2 = adj[st+j+2], s3 = adj[st+j+3];
      a0 += x[(size_t)s0*64 + lane];
      a1 += x[(size_t)s1*64 + lane];
      a2 += x[(size_t)s2*64 + lane];
      a3 += x[(size_t)s3*64 + lane];
    }
    for (; j < d; j++) a0 += x[(size_t)adj[st+j]*64 + lane];
    agg[(size_t)n*64 + lane] = (a0 + a1) + (a2 + a3);
  }
}

__global__ __launch_bounds__(256) void k_gather14(const float* __restrict__ x, const int* __restrict__ row_ptr,
                                                  const int* __restrict__ cnt, const int* __restrict__ adj,
                                                  float* __restrict__ agg){
  const int lane = threadIdx.x & 63;
  const int f = lane & 15, g = lane >> 4;
  const int wave = blockIdx.x*4 + (threadIdx.x >> 6);
  const int nwav = gridDim.x*4;
  for (int n = wave; n < NN; n += nwav){
    int st = row_ptr[n], d = cnt[n];
    float acc = 0.0f;
    for (int j = g; j < d; j += 4){
      int s = adj[st+j];
      if (f < 14) acc += x[(size_t)s*14 + f];
    }
    acc += __shfl_down(acc, 32);
    acc += __shfl_down(acc, 16);
    if (lane < 14) agg[(size_t)n*14 + lane] = acc;
  }
}

// ---------------- BN-fold weight prep ----------------
// wbuf: Wn'(din*64, [k][j]) | Wr'(din*64) | b_base(64) | b_agg(64)
__global__ __launch_bounds__(256) void k_prep(const float* __restrict__ Wn, const float* __restrict__ Wr,
                                              const float* __restrict__ b, const float* __restrict__ stats,
                                              const float* __restrict__ g, const float* __restrict__ be,
                                              float* __restrict__ wbuf, int din){
  __shared__ float sc[64], sh[64];
  int t = threadIdx.x;
  if (t < 64){
    float a = 1.0f, s0 = 0.0f;
    if (stats){
      float m = stats[t] * (1.0f/NN);
      float v = stats[64+t] * (1.0f/NN) - m*m;
      a  = g[t] * rsqrtf(v + EPSV);
      s0 = be[t] - m*a;
    }
    sc[t] = a; sh[t] = s0;
  }
  __syncthreads();
  for (int i = t; i < din*64; i += 256){
    int k = i >> 6;
    wbuf[i]          = sc[k]*Wn[i];
    wbuf[din*64 + i] = sc[k]*Wr[i];
  }
  if (t < 64){
    float accB = b ? b[t] : 0.0f;
    float accN = 0.0f;
    for (int k=0;k<din;k++){
      accB += sh[k]*Wr[k*64+t];
      accN += sh[k]*Wn[k*64+t];
    }
    wbuf[2*din*64 + t]      = accB;
    wbuf[2*din*64 + 64 + t] = accN;
  }
}

__device__ __forceinline__ float act_f(float z, int ACT){
  if (ACT == 1) return z > 0.0f ? z : 0.01f*z;
  if (ACT == 2) return fmaxf(z, 0.0f);
  return z;
}

// ---------------- conv GEMM: lane = node, W via scalar pipe ----------------
// out[n][j] = 1{deg>0}(iv*(agg[n]@Wn')[j] + b_agg[j]) + (x[n]@Wr')[j] + b_base[j], act.
// Block 128 thr = 128 nodes. Rows staged in LDS (stride DIN+1, conflict-free),
// W rows read wave-uniform -> s_load (scalar cache), acc[64]/lane in VGPRs.
template<int DIN, int ACT>
__global__ __launch_bounds__(128, 1) void k_gemm_conv(const float* __restrict__ agg, const float* __restrict__ x,
                                                      const float* __restrict__ invdeg, const float* __restrict__ wbuf,
                                                      float* __restrict__ out){
  constexpr int RS = DIN + 1;
  __shared__ float sRow[128*RS];
  const int tid = threadIdx.x;
  const int n0  = blockIdx.x*128;
  const int n   = n0 + tid;

  // stage agg rows (coalesced b32, padded stride)
  {
    const float* gp = agg + (size_t)n0*DIN;
    for (int i = tid; i < 128*DIN; i += 128){
      int r = i / DIN, c = i - r*DIN;
      sRow[r*RS + c] = (n0 + r < NN) ? gp[i] : 0.0f;
    }
  }
  __syncthreads();

  float accA0[32], accA1[32];
  #pragma unroll
  for (int jj=0;jj<32;jj++){ accA0[jj]=0.0f; accA1[jj]=0.0f; }

  #pragma unroll 1
  for (int k=0;k<DIN;k++){
    float rv = sRow[tid*RS + k];
    const float* wr = wbuf + k*64;          // wave-uniform -> s_load
    #pragma unroll
    for (int jj=0;jj<32;jj++) accA0[jj] = fmaf(wr[jj],    rv, accA0[jj]);
    #pragma unroll
    for (int jj=0;jj<32;jj++) accA1[jj] = fmaf(wr[32+jj], rv, accA1[jj]);
  }
  __syncthreads();

  // stage x rows over same LDS
  {
    const float* gp = x + (size_t)n0*DIN;
    for (int i = tid; i < 128*DIN; i += 128){
      int r = i / DIN, c = i - r*DIN;
      sRow[r*RS + c] = (n0 + r < NN) ? gp[i] : 0.0f;
    }
  }
  __syncthreads();

  // gate + scale the aggregation part
  float iv = (n < NN) ? invdeg[n] : -1.0f;
  const bool gate = iv > 0.0f;
  const float* bagg = wbuf + 2*DIN*64 + 64;
  #pragma unroll
  for (int jj=0;jj<32;jj++){
    accA0[jj] = gate ? fmaf(accA0[jj], iv, bagg[jj])    : 0.0f;
    accA1[jj] = gate ? fmaf(accA1[jj], iv, bagg[32+jj]) : 0.0f;
  }

  #pragma unroll 1
  for (int k=0;k<DIN;k++){
    float rv = sRow[tid*RS + k];
    const float* wr = wbuf + DIN*64 + k*64;
    #pragma unroll
    for (int jj=0;jj<32;jj++) accA0[jj] = fmaf(wr[jj],    rv, accA0[jj]);
    #pragma unroll
    for (int jj=0;jj<32;jj++) accA1[jj] = fmaf(wr[32+jj], rv, accA1[jj]);
  }

  const float* bb = wbuf + 2*DIN*64;
  if (n < NN){
    float4* o4 = (float4*)(out + (size_t)n*64);
    #pragma unroll
    for (int q=0;q<8;q++){
      float4 t;
      t.x = act_f(accA0[4*q+0] + bb[4*q+0], ACT);
      t.y = act_f(accA0[4*q+1] + bb[4*q+1], ACT);
      t.z = act_f(accA0[4*q+2] + bb[4*q+2], ACT);
      t.w = act_f(accA0[4*q+3] + bb[4*q+3], ACT);
      o4[q] = t;
    }
    #pragma unroll
    for (int q=0;q<8;q++){
      float4 t;
      t.x = act_f(accA1[4*q+0] + bb[32+4*q+0], ACT);
      t.y = act_f(accA1[4*q+1] + bb[32+4*q+1], ACT);
      t.z = act_f(accA1[4*q+2] + bb[32+4*q+2], ACT);
      t.w = act_f(accA1[4*q+3] + bb[32+4*q+3], ACT);
      o4[8+q] = t;
    }
  }
}

// ---------------- linear: lane = node, DIN fixed 64 ----------------
template<int DOUT, bool BIAS>
__global__ __launch_bounds__(128, 1) void k_gemm_lin(const float* __restrict__ x, const float* __restrict__ W,
                                                     const float* __restrict__ bias, float* __restrict__ out){
  __shared__ float sRow[128*65];
  const int tid = threadIdx.x;
  const int n0  = blockIdx.x*128;
  const int n   = n0 + tid;
  {
    const float* gp = x + (size_t)n0*64;
    for (int i = tid; i < 128*64; i += 128){
      int r = i >> 6, c = i & 63;
      sRow[r*65 + c] = (n0 + r < NN) ? gp[i] : 0.0f;
    }
  }
  __syncthreads();

  if constexpr (DOUT == 64){
    float a0[32], a1[32];
    #pragma unroll
    for (int jj=0;jj<32;jj++){ a0[jj]=0.0f; a1[jj]=0.0f; }
    #pragma unroll 1
    for (int k=0;k<64;k++){
      float rv = sRow[tid*65 + k];
      const float* wr = W + k*64;
      #pragma unroll
      for (int jj=0;jj<32;jj++) a0[jj] = fmaf(wr[jj],    rv, a0[jj]);
      #pragma unroll
      for (int jj=0;jj<32;jj++) a1[jj] = fmaf(wr[32+jj], rv, a1[jj]);
    }
    if (n < NN){
      float4* o4 = (float4*)(out + (size_t)n*64);
      #pragma unroll
      for (int q=0;q<8;q++){
        float4 t;
        t.x = a0[4*q+0] + (BIAS ? bias[4*q+0] : 0.0f);
        t.y = a0[4*q+1] + (BIAS ? bias[4*q+1] : 0.0f);
        t.z = a0[4*q+2] + (BIAS ? bias[4*q+2] : 0.0f);
        t.w = a0[4*q+3] + (BIAS ? bias[4*q+3] : 0.0f);
        o4[q] = t;
      }
      #pragma unroll
      for (int q=0;q<8;q++){
        float4 t;
        t.x = a1[4*q+0] + (BIAS ? bias[32+4*q+0] : 0.0f);
        t.y = a1[4*q+1] + (BIAS ? bias[32+4*q+1] : 0.0f);
        t.z = a1[4*q+2] + (BIAS ? bias[32+4*q+2] : 0.0f);
        t.w = a1[4*q+3] + (BIAS ? bias[32+4*q+3] : 0.0f);
        o4[8+q] = t;
      }
    }
  } else {
    float a[DOUT];
    #pragma unroll
    for (int jj=0;jj<DOUT;jj++) a[jj] = 0.0f;
    #pragma unroll 1
    for (int k=0;k<64;k++){
      float rv = sRow[tid*65 + k];
      const float* wr = W + k*DOUT;
      #pragma unroll
      for (int jj=0;jj<DOUT;jj++) a[jj] = fmaf(wr[jj], rv, a[jj]);
    }
    if (n < NN){
      #pragma unroll
      for (int jj=0;jj<DOUT;jj++)
        out[(size_t)n*DOUT + jj] = a[jj] + (BIAS ? bias[jj] : 0.0f);
    }
  }
}

// ---------------- per-feature stats pass (sum, sumsq) ----------------
__global__ __launch_bounds__(256) void k_stats(const float* __restrict__ h, float* __restrict__ st){
  __shared__ float sm[512];
  const int tid = threadIdx.x;
  size_t idx = (size_t)blockIdx.x*256 + tid;
  const size_t stride = (size_t)gridDim.x*256;   // multiple of 64 -> feature invariant
  float ls = 0.0f, lss = 0.0f;
  for (size_t i = idx; i < (size_t)NN*64; i += stride){
    float z = h[i];
    ls += z; lss = fmaf(z, z, lss);
  }
  const int f = tid & 63, wv = tid >> 6;
  sm[wv*128 + f]      = ls;
  sm[wv*128 + 64 + f] = lss;
  __syncthreads();
  if (tid < 128){
    float v = sm[tid] + sm[128+tid] + sm[256+tid] + sm[384+tid];
    atomicAdd(&st[tid], v);
  }
}

__global__ __launch_bounds__(256) void k_normrelu(float* __restrict__ h, const float* __restrict__ stats,
                                                  const float* __restrict__ g, const float* __restrict__ be){
  size_t idx = (size_t)blockIdx.x*256 + threadIdx.x;
  int f = (int)(idx & 63);
  float m = stats[f] * (1.0f/NN);
  float v = stats[64+f] * (1.0f/NN) - m*m;
  float a = g[f]*rsqrtf(v+EPSV);
  float b = be[f] - m*a;
  float z = h[idx];
  h[idx] = fmaxf(fmaf(a, z, b), 0.0f);
}

extern "C" void kernel_launch(void* const* d_in, const int* in_sizes, int n_in,
                              void* d_out, int out_size, void* d_ws, size_t ws_size,
                              hipStream_t stream){
  const float* x1  = (const float*)d_in[0];
  const int*   ei  = (const int*)d_in[1];
  const int* srcp = ei;
  const int* dstp = ei + EE;
  const float *Wn1=(const float*)d_in[2],  *Wr1=(const float*)d_in[3],  *b1=(const float*)d_in[4];
  const float *Wn2=(const float*)d_in[5],  *Wr2=(const float*)d_in[6],  *b2=(const float*)d_in[7];
  const float *Wn3=(const float*)d_in[8],  *Wr3=(const float*)d_in[9],  *b3=(const float*)d_in[10];
  const float *Wn4=(const float*)d_in[11], *Wr4=(const float*)d_in[12], *b4=(const float*)d_in[13];
  const float *g1=(const float*)d_in[14], *be1=(const float*)d_in[15];
  const float *g2=(const float*)d_in[16], *be2=(const float*)d_in[17];
  const float *g3=(const float*)d_in[18], *be3=(const float*)d_in[19];
  const float *Wm0=(const float*)d_in[20], *gm0=(const float*)d_in[21], *bem0=(const float*)d_in[22];
  const float *Wm1=(const float*)d_in[23], *gm1=(const float*)d_in[24], *bem1=(const float*)d_in[25];
  const float *Wm2=(const float*)d_in[26], *bm2=(const float*)d_in[27];
  float* out = (float*)d_out;

  char* ws = (char*)d_ws;
  int*   cnt     = (int*)(ws);
  int*   row_ptr = (int*)(ws + (1ull<<20));
  int*   cursor  = (int*)(ws + (2ull<<20));
  int*   pre     = (int*)(ws + (3ull<<20));
  int*   blksum  = (int*)(ws + (4ull<<20));
  float* invdeg  = (float*)(ws + (5ull<<20));
  int*   adj     = (int*)(ws + (6ull<<20));
  float* agg     = (float*)(ws + (12ull<<20));
  float* hA      = (float*)(ws + (43ull<<20));
  float* hB      = (float*)(ws + (74ull<<20));
  float* stats   = (float*)(ws + (105ull<<20));
  float* wbuf    = (float*)(ws + (105ull<<20) + 8192);

  hipMemsetAsync(cnt, 0, NN*sizeof(int), stream);
  hipMemsetAsync(stats, 0, 5*128*sizeof(float), stream);
  k_count<<<(EE+255)/256,256,0,stream>>>(dstp, cnt);
  k_scan1<<<NB_SCAN,256,0,stream>>>(cnt, pre, blksum);
  k_scan2<<<1,512,0,stream>>>(blksum);
  k_scan3<<<NB_SCAN,256,0,stream>>>(pre, blksum, cnt, row_ptr, cursor, invdeg);
  k_fill<<<(EE+255)/256,256,0,stream>>>(srcp, dstp, cursor, adj);

  // conv1 (din=14, lrelu) -> hA ; stats S1
  k_gather14<<<2048,256,0,stream>>>(x1, row_ptr, cnt, adj, agg);
  k_prep<<<1,256,0,stream>>>(Wn1,Wr1,b1,nullptr,nullptr,nullptr,wbuf,14);
  k_gemm_conv<14,1><<<NCBLK,128,0,stream>>>(agg,x1,invdeg,wbuf,hA);
  k_stats<<<512,256,0,stream>>>(hA, stats);

  // conv2 (BN1 folded, lrelu) -> hB ; stats S2
  k_gather64<<<2048,256,0,stream>>>(hA, row_ptr, cnt, adj, agg);
  k_prep<<<1,256,0,stream>>>(Wn2,Wr2,b2,stats,g1,be1,wbuf,64);
  k_gemm_conv<64,1><<<NCBLK,128,0,stream>>>(agg,hA,invdeg,wbuf,hB);
  k_stats<<<512,256,0,stream>>>(hB, stats+128);

  // conv3 (BN2 folded, relu) -> hA ; stats S3
  k_gather64<<<2048,256,0,stream>>>(hB, row_ptr, cnt, adj, agg);
  k_prep<<<1,256,0,stream>>>(Wn3,Wr3,b3,stats+128,g2,be2,wbuf,64);
  k_gemm_conv<64,2><<<NCBLK,128,0,stream>>>(agg,hB,invdeg,wbuf,hA);
  k_stats<<<512,256,0,stream>>>(hA, stats+256);

  // conv4 (BN3 folded, no act) -> hB
  k_gather64<<<2048,256,0,stream>>>(hA, row_ptr, cnt, adj, agg);
  k_prep<<<1,256,0,stream>>>(Wn4,Wr4,b4,stats+256,g3,be3,wbuf,64);
  k_gemm_conv<64,0><<<NCBLK,128,0,stream>>>(agg,hA,invdeg,wbuf,hB);

  // MLP head
  k_gemm_lin<64,false><<<NCBLK,128,0,stream>>>(hB,Wm0,nullptr,hA);
  k_stats<<<512,256,0,stream>>>(hA, stats+384);
  k_normrelu<<<(NN*64)/256,256,0,stream>>>(hA,stats+384,gm0,bem0);
  k_gemm_lin<64,false><<<NCBLK,128,0,stream>>>(hA,Wm1,nullptr,hB);
  k_stats<<<512,256,0,stream>>>(hB, stats+512);
  k_normrelu<<<(NN*64)/256,256,0,stream>>>(hB,stats+512,gm1,bem1);
  k_gemm_lin<21,true><<<NCBLK,128,0,stream>>>(hB,Wm2,bm2,out);
}

// Round 7
// 757.519 us; speedup vs baseline: 1.4086x; 1.4086x over previous
//
#include <hip/hip_runtime.h>

constexpr int NN = 120000;
constexpr int EE = 1200000;
constexpr float EPSV = 1e-5f;
constexpr int NB_SCAN = (NN + 255) / 256;   // 469
constexpr int NCBLK   = (NN + 127) / 128;   // 938
constexpr int NTILES  = NN / 16;            // 7500 exact
constexpr int NMFMABLK = NTILES / 4;        // 1875 exact

typedef __attribute__((ext_vector_type(8))) short bf8v;
typedef __attribute__((ext_vector_type(4))) float f4v;

__device__ __forceinline__ float bf2f(unsigned short u){
  union { unsigned i; float f; } v; v.i = ((unsigned)u) << 16; return v.f;
}
__device__ __forceinline__ unsigned short f2bf(float f){
  union { float f; unsigned i; } v; v.f = f;
  unsigned u = v.i;
  return (unsigned short)((u + 0x7FFFu + ((u >> 16) & 1u)) >> 16);
}
__device__ __forceinline__ unsigned pack2(float a, float b){
  return (unsigned)f2bf(a) | ((unsigned)f2bf(b) << 16);
}
__device__ __forceinline__ float act_f(float z, int ACT){
  if (ACT == 1) return z > 0.0f ? z : 0.01f*z;
  if (ACT == 2) return fmaxf(z, 0.0f);
  return z;
}

// ---------------- CSR build ----------------
__global__ __launch_bounds__(256) void k_count(const int* __restrict__ dst, int* __restrict__ cnt){
  int e = blockIdx.x*256 + threadIdx.x;
  if (e < EE) atomicAdd(&cnt[dst[e]], 1);
}

__global__ __launch_bounds__(256) void k_scan1(const int* __restrict__ cnt, int* __restrict__ pre,
                                               int* __restrict__ blksum){
  __shared__ int sm[256];
  int i = blockIdx.x*256 + threadIdx.x;
  int v = (i < NN) ? cnt[i] : 0;
  sm[threadIdx.x] = v; __syncthreads();
  for (int off = 1; off < 256; off <<= 1){
    int t = (threadIdx.x >= off) ? sm[threadIdx.x - off] : 0;
    __syncthreads();
    sm[threadIdx.x] += t;
    __syncthreads();
  }
  if (i < NN) pre[i] = sm[threadIdx.x] - v;
  if (threadIdx.x == 255) blksum[blockIdx.x] = sm[255];
}

__global__ __launch_bounds__(512) void k_scan2(int* __restrict__ blksum){
  __shared__ int sm[512];
  int v = (threadIdx.x < NB_SCAN) ? blksum[threadIdx.x] : 0;
  sm[threadIdx.x] = v; __syncthreads();
  for (int off = 1; off < 512; off <<= 1){
    int t = (threadIdx.x >= off) ? sm[threadIdx.x - off] : 0;
    __syncthreads();
    sm[threadIdx.x] += t;
    __syncthreads();
  }
  if (threadIdx.x < NB_SCAN) blksum[threadIdx.x] = sm[threadIdx.x] - v;
}

__global__ __launch_bounds__(256) void k_scan3(const int* __restrict__ pre, const int* __restrict__ blksum,
                                               const int* __restrict__ cnt,
                                               int* __restrict__ row_ptr, int* __restrict__ cursor,
                                               float* __restrict__ invdeg){
  int i = blockIdx.x*256 + threadIdx.x;
  if (i < NN){
    int r = pre[i] + blksum[blockIdx.x];
    row_ptr[i] = r; cursor[i] = r;
    int c = cnt[i];
    invdeg[i] = (c > 0) ? (1.0f/(float)c) : -1.0f;
  }
}

__global__ __launch_bounds__(256) void k_fill(const int* __restrict__ src, const int* __restrict__ dst,
                                              int* __restrict__ cursor, int* __restrict__ adj){
  int e = blockIdx.x*256 + threadIdx.x;
  if (e < EE){
    int p = atomicAdd(&cursor[dst[e]], 1);
    adj[p] = src[e];
  }
}

// ---------------- gather: bf16 rows, folds the mean (deg-0 rows -> 0) ----------------
__global__ __launch_bounds__(256) void k_gather64b(const unsigned short* __restrict__ x,
                                                   const int* __restrict__ row_ptr,
                                                   const int* __restrict__ cnt, const int* __restrict__ adj,
                                                   const float* __restrict__ invdeg,
                                                   unsigned short* __restrict__ aggm){
  const int lane = threadIdx.x & 63;
  const int wave = blockIdx.x*4 + (threadIdx.x >> 6);
  const int nwav = gridDim.x*4;
  for (int n = wave; n < NN; n += nwav){
    int st = row_ptr[n], d = cnt[n];
    float a0 = 0.0f, a1 = 0.0f, a2 = 0.0f, a3 = 0.0f;
    int j = 0;
    for (; j + 3 < d; j += 4){
      int s0 = adj[st+j], s1 = adj[st+j+1], s2 = adj[st+j+2], s3 = adj[st+j+3];
      a0 += bf2f(x[(size_t)s0*64 + lane]);
      a1 += bf2f(x[(size_t)s1*64 + lane]);
      a2 += bf2f(x[(size_t)s2*64 + lane]);
      a3 += bf2f(x[(size_t)s3*64 + lane]);
    }
    for (; j < d; j++) a0 += bf2f(x[(size_t)adj[st+j]*64 + lane]);
    float iv = fmaxf(invdeg[n], 0.0f);
    aggm[(size_t)n*64 + lane] = f2bf(((a0 + a1) + (a2 + a3)) * iv);
  }
}

// fp32 gather for layer 1 (din=14, sums)
__global__ __launch_bounds__(256) void k_gather14(const float* __restrict__ x, const int* __restrict__ row_ptr,
                                                  const int* __restrict__ cnt, const int* __restrict__ adj,
                                                  float* __restrict__ agg){
  const int lane = threadIdx.x & 63;
  const int f = lane & 15, g = lane >> 4;
  const int wave = blockIdx.x*4 + (threadIdx.x >> 6);
  const int nwav = gridDim.x*4;
  for (int n = wave; n < NN; n += nwav){
    int st = row_ptr[n], d = cnt[n];
    float acc = 0.0f;
    for (int j = g; j < d; j += 4){
      int s = adj[st+j];
      if (f < 14) acc += x[(size_t)s*14 + f];
    }
    acc += __shfl_down(acc, 32);
    acc += __shfl_down(acc, 16);
    if (lane < 14) agg[(size_t)n*14 + lane] = acc;
  }
}

// ---------------- fp32 BN-fold prep (layer 1 scalar path) ----------------
// wbuf: Wn'(din*64) | Wr'(din*64) | b_base(64) | b_agg(64)
__global__ __launch_bounds__(256) void k_prep(const float* __restrict__ Wn, const float* __restrict__ Wr,
                                              const float* __restrict__ b, const float* __restrict__ stats,
                                              const float* __restrict__ g, const float* __restrict__ be,
                                              float* __restrict__ wbuf, int din){
  __shared__ float sc[64], sh[64];
  int t = threadIdx.x;
  if (t < 64){
    float a = 1.0f, s0 = 0.0f;
    if (stats){
      float m = stats[t] * (1.0f/NN);
      float v = stats[64+t] * (1.0f/NN) - m*m;
      a  = g[t] * rsqrtf(v + EPSV);
      s0 = be[t] - m*a;
    }
    sc[t] = a; sh[t] = s0;
  }
  __syncthreads();
  for (int i = t; i < din*64; i += 256){
    int k = i >> 6;
    wbuf[i]          = sc[k]*Wn[i];
    wbuf[din*64 + i] = sc[k]*Wr[i];
  }
  if (t < 64){
    float accB = b ? b[t] : 0.0f;
    float accN = 0.0f;
    for (int k=0;k<din;k++){
      accB += sh[k]*Wr[k*64+t];
      accN += sh[k]*Wn[k*64+t];
    }
    wbuf[2*din*64 + t]      = accB;
    wbuf[2*din*64 + 64 + t] = accN;
  }
}

// ---------------- MFMA weight prep: BN-fold + pack B-fragments (conv layers) ----------------
// frag elem addr: (((mat*4+ct)*2+kk)*64 + lane)*8 + j ; B[k][col], k=kk*32+(lane>>4)*8+j, col=ct*16+(lane&15)
__global__ __launch_bounds__(256) void k_prep_conv_frag(const float* __restrict__ Wn, const float* __restrict__ Wr,
                                                        const float* __restrict__ b, const float* __restrict__ stats,
                                                        const float* __restrict__ g, const float* __restrict__ be,
                                                        unsigned short* __restrict__ frag, float* __restrict__ bias2){
  __shared__ float sc[64], sh[64];
  int t = threadIdx.x;
  if (t < 64){
    float m = stats[t] * (1.0f/NN);
    float v = stats[64+t] * (1.0f/NN) - m*m;
    float a = g[t] * rsqrtf(v + EPSV);
    sc[t] = a; sh[t] = be[t] - m*a;
  }
  __syncthreads();
  if (t < 64){
    float accB = b[t], accN = 0.0f;
    for (int k=0;k<64;k++){
      accB += sh[k]*Wr[k*64+t];
      accN += sh[k]*Wn[k*64+t];
    }
    bias2[t]      = accB;
    bias2[64 + t] = accN;
  }
  for (int it = 0; it < 32; it++){
    int idx = it*256 + t;          // 8192 total
    int j    = idx & 7;
    int lane = (idx >> 3) & 63;
    int kk   = (idx >> 9) & 1;
    int ct   = (idx >> 10) & 3;
    int mat  = (idx >> 12) & 1;
    int k    = kk*32 + (lane >> 4)*8 + j;
    int col  = ct*16 + (lane & 15);
    const float* W = mat ? Wr : Wn;
    frag[idx] = f2bf(sc[k] * W[k*64 + col]);
  }
}

// pack B-fragments for a plain 64x64 matrix (MLP linears), zero biases
__global__ __launch_bounds__(256) void k_prep_lin_frag(const float* __restrict__ W,
                                                       unsigned short* __restrict__ frag,
                                                       float* __restrict__ bias2){
  int t = threadIdx.x;
  if (t < 128) bias2[t] = 0.0f;
  for (int it = 0; it < 16; it++){
    int idx = it*256 + t;          // 4096 total
    int j    = idx & 7;
    int lane = (idx >> 3) & 63;
    int kk   = (idx >> 9) & 1;
    int ct   = (idx >> 10) & 3;
    int k    = kk*32 + (lane >> 4)*8 + j;
    int col  = ct*16 + (lane & 15);
    frag[idx] = f2bf(W[k*64 + col]);
  }
}

// ---------------- MFMA GEMM: out[n][:] = mean@Wn' + x@Wr' + bb + gate*bagg, act ----------------
// One wave per 16-node tile; B-frags in VGPRs; A-frags straight from global bf16 rows.
template<bool DUAL, int ACT>
__global__ __launch_bounds__(256, 1) void k_mfma(const unsigned short* __restrict__ Am,
                                                 const unsigned short* __restrict__ Ax,
                                                 const float* __restrict__ invdeg,
                                                 const unsigned short* __restrict__ frag,
                                                 const float* __restrict__ bias2,
                                                 unsigned short* __restrict__ out){
  const int lane = threadIdx.x & 63;
  const int wv   = threadIdx.x >> 6;
  const int tile = blockIdx.x*4 + wv;       // 7500 exact
  const int n0   = tile*16;
  const int m    = lane & 15;
  const int kq   = lane >> 4;

  const bf8v* fp = (const bf8v*)frag;
  bf8v wn[4][2], wr[4][2];
  #pragma unroll
  for (int ct=0;ct<4;ct++){
    #pragma unroll
    for (int kk=0;kk<2;kk++){
      if constexpr (DUAL){
        wn[ct][kk] = fp[((0*4+ct)*2+kk)*64 + lane];
        wr[ct][kk] = fp[((1*4+ct)*2+kk)*64 + lane];
      } else {
        wr[ct][kk] = fp[((0*4+ct)*2+kk)*64 + lane];
      }
    }
  }

  const size_t arow = (size_t)(n0 + m)*64;
  bf8v ax0 = *(const bf8v*)(Ax + arow + kq*8);
  bf8v ax1 = *(const bf8v*)(Ax + arow + 32 + kq*8);
  bf8v am0, am1;
  if constexpr (DUAL){
    am0 = *(const bf8v*)(Am + arow + kq*8);
    am1 = *(const bf8v*)(Am + arow + 32 + kq*8);
  }

  f4v acc[4];
  #pragma unroll
  for (int ct=0;ct<4;ct++){
    f4v c = {0.0f,0.0f,0.0f,0.0f};
    if constexpr (DUAL){
      c = __builtin_amdgcn_mfma_f32_16x16x32_bf16(am0, wn[ct][0], c, 0,0,0);
      c = __builtin_amdgcn_mfma_f32_16x16x32_bf16(am1, wn[ct][1], c, 0,0,0);
    }
    c = __builtin_amdgcn_mfma_f32_16x16x32_bf16(ax0, wr[ct][0], c, 0,0,0);
    c = __builtin_amdgcn_mfma_f32_16x16x32_bf16(ax1, wr[ct][1], c, 0,0,0);
    acc[ct] = c;
  }

  // epilogue: C/D layout col=lane&15, row=(lane>>4)*4+reg  [guide §3, m89-verified]
  const int col = lane & 15;
  float bb[4], bg[4];
  #pragma unroll
  for (int ct=0;ct<4;ct++){
    bb[ct] = bias2[ct*16 + col];
    if (DUAL) bg[ct] = bias2[64 + ct*16 + col];
  }
  #pragma unroll
  for (int r=0;r<4;r++){
    const int node = n0 + (lane>>4)*4 + r;
    float gadd = 0.0f;
    if constexpr (DUAL) gadd = (invdeg[node] > 0.0f) ? 1.0f : 0.0f;
    #pragma unroll
    for (int ct=0;ct<4;ct++){
      float z = acc[ct][r] + bb[ct];
      if (DUAL) z += gadd * bg[ct];
      z = act_f(z, ACT);
      out[(size_t)node*64 + ct*16 + col] = f2bf(z);
    }
  }
}

// ---------------- conv1 scalar GEMM (din=14, fp32 in, bf16 out, lrelu) ----------------
__global__ __launch_bounds__(128, 1) void k_gemm_conv14(const float* __restrict__ agg, const float* __restrict__ x,
                                                        const float* __restrict__ invdeg, const float* __restrict__ wbuf,
                                                        unsigned short* __restrict__ out){
  constexpr int DIN = 14, RS = 15;
  __shared__ float sRow[128*RS];
  const int tid = threadIdx.x;
  const int n0  = blockIdx.x*128;
  const int n   = n0 + tid;

  {
    const float* gp = agg + (size_t)n0*DIN;
    for (int i = tid; i < 128*DIN; i += 128){
      int r = i / DIN, c = i - r*DIN;
      sRow[r*RS + c] = (n0 + r < NN) ? gp[i] : 0.0f;
    }
  }
  __syncthreads();

  float accA0[32], accA1[32];
  #pragma unroll
  for (int jj=0;jj<32;jj++){ accA0[jj]=0.0f; accA1[jj]=0.0f; }

  #pragma unroll 1
  for (int k=0;k<DIN;k++){
    float rv = sRow[tid*RS + k];
    const float* wr = wbuf + k*64;
    #pragma unroll
    for (int jj=0;jj<32;jj++) accA0[jj] = fmaf(wr[jj],    rv, accA0[jj]);
    #pragma unroll
    for (int jj=0;jj<32;jj++) accA1[jj] = fmaf(wr[32+jj], rv, accA1[jj]);
  }
  __syncthreads();
  {
    const float* gp = x + (size_t)n0*DIN;
    for (int i = tid; i < 128*DIN; i += 128){
      int r = i / DIN, c = i - r*DIN;
      sRow[r*RS + c] = (n0 + r < NN) ? gp[i] : 0.0f;
    }
  }
  __syncthreads();

  float iv = (n < NN) ? invdeg[n] : -1.0f;
  const bool gate = iv > 0.0f;
  const float* bagg = wbuf + 2*DIN*64 + 64;
  #pragma unroll
  for (int jj=0;jj<32;jj++){
    accA0[jj] = gate ? fmaf(accA0[jj], iv, bagg[jj])    : 0.0f;
    accA1[jj] = gate ? fmaf(accA1[jj], iv, bagg[32+jj]) : 0.0f;
  }

  #pragma unroll 1
  for (int k=0;k<DIN;k++){
    float rv = sRow[tid*RS + k];
    const float* wr = wbuf + DIN*64 + k*64;
    #pragma unroll
    for (int jj=0;jj<32;jj++) accA0[jj] = fmaf(wr[jj],    rv, accA0[jj]);
    #pragma unroll
    for (int jj=0;jj<32;jj++) accA1[jj] = fmaf(wr[32+jj], rv, accA1[jj]);
  }

  const float* bb = wbuf + 2*DIN*64;
  if (n < NN){
    uint2* o2 = (uint2*)(out + (size_t)n*64);
    #pragma unroll
    for (int q=0;q<8;q++){
      uint2 t;
      t.x = pack2(act_f(accA0[4*q+0]+bb[4*q+0],1), act_f(accA0[4*q+1]+bb[4*q+1],1));
      t.y = pack2(act_f(accA0[4*q+2]+bb[4*q+2],1), act_f(accA0[4*q+3]+bb[4*q+3],1));
      o2[q] = t;
    }
    #pragma unroll
    for (int q=0;q<8;q++){
      uint2 t;
      t.x = pack2(act_f(accA1[4*q+0]+bb[32+4*q+0],1), act_f(accA1[4*q+1]+bb[32+4*q+1],1));
      t.y = pack2(act_f(accA1[4*q+2]+bb[32+4*q+2],1), act_f(accA1[4*q+3]+bb[32+4*q+3],1));
      o2[8+q] = t;
    }
  }
}

// ---------------- final linear 64->21, bf16 in, fp32 out ----------------
__global__ __launch_bounds__(128, 1) void k_lin21(const unsigned short* __restrict__ x,
                                                  const float* __restrict__ W, const float* __restrict__ bias,
                                                  float* __restrict__ out){
  __shared__ float sRow[128*65];
  const int tid = threadIdx.x;
  const int n0  = blockIdx.x*128;
  const int n   = n0 + tid;
  {
    const unsigned short* gp = x + (size_t)n0*64;
    for (int i = tid; i < 128*64; i += 128){
      int r = i >> 6, c = i & 63;
      sRow[r*65 + c] = (n0 + r < NN) ? bf2f(gp[i]) : 0.0f;
    }
  }
  __syncthreads();
  float a[21];
  #pragma unroll
  for (int jj=0;jj<21;jj++) a[jj] = 0.0f;
  #pragma unroll 1
  for (int k=0;k<64;k++){
    float rv = sRow[tid*65 + k];
    const float* wr = W + k*21;
    #pragma unroll
    for (int jj=0;jj<21;jj++) a[jj] = fmaf(wr[jj], rv, a[jj]);
  }
  if (n < NN){
    #pragma unroll
    for (int jj=0;jj<21;jj++) out[(size_t)n*21 + jj] = a[jj] + bias[jj];
  }
}

// ---------------- per-feature stats over bf16 h ----------------
__global__ __launch_bounds__(256) void k_stats(const unsigned short* __restrict__ h, float* __restrict__ st){
  __shared__ float sm[512];
  const int tid = threadIdx.x;
  size_t idx = (size_t)blockIdx.x*256 + tid;
  const size_t stride = (size_t)gridDim.x*256;
  float ls = 0.0f, lss = 0.0f;
  for (size_t i = idx; i < (size_t)NN*64; i += stride){
    float z = bf2f(h[i]);
    ls += z; lss = fmaf(z, z, lss);
  }
  const int f = tid & 63, wv = tid >> 6;
  sm[wv*128 + f]      = ls;
  sm[wv*128 + 64 + f] = lss;
  __syncthreads();
  if (tid < 128){
    float v = sm[tid] + sm[128+tid] + sm[256+tid] + sm[384+tid];
    atomicAdd(&st[tid], v);
  }
}

__global__ __launch_bounds__(256) void k_normrelu(unsigned short* __restrict__ h, const float* __restrict__ stats,
                                                  const float* __restrict__ g, const float* __restrict__ be){
  size_t i4 = ((size_t)blockIdx.x*256 + threadIdx.x)*4;
  int f0 = (int)(i4 & 63);
  uint2 p = *(uint2*)(h + i4);
  unsigned short e[4] = {(unsigned short)(p.x & 0xFFFF), (unsigned short)(p.x >> 16),
                         (unsigned short)(p.y & 0xFFFF), (unsigned short)(p.y >> 16)};
  unsigned short o[4];
  #pragma unroll
  for (int i=0;i<4;i++){
    int f = f0 + i;
    float m = stats[f] * (1.0f/NN);
    float v = stats[64+f] * (1.0f/NN) - m*m;
    float a = g[f]*rsqrtf(v+EPSV);
    float b = be[f] - m*a;
    o[i] = f2bf(fmaxf(fmaf(a, bf2f(e[i]), b), 0.0f));
  }
  uint2 q;
  q.x = (unsigned)o[0] | ((unsigned)o[1] << 16);
  q.y = (unsigned)o[2] | ((unsigned)o[3] << 16);
  *(uint2*)(h + i4) = q;
}

extern "C" void kernel_launch(void* const* d_in, const int* in_sizes, int n_in,
                              void* d_out, int out_size, void* d_ws, size_t ws_size,
                              hipStream_t stream){
  const float* x1  = (const float*)d_in[0];
  const int*   ei  = (const int*)d_in[1];
  const int* srcp = ei;
  const int* dstp = ei + EE;
  const float *Wn1=(const float*)d_in[2],  *Wr1=(const float*)d_in[3],  *b1=(const float*)d_in[4];
  const float *Wn2=(const float*)d_in[5],  *Wr2=(const float*)d_in[6],  *b2=(const float*)d_in[7];
  const float *Wn3=(const float*)d_in[8],  *Wr3=(const float*)d_in[9],  *b3=(const float*)d_in[10];
  const float *Wn4=(const float*)d_in[11], *Wr4=(const float*)d_in[12], *b4=(const float*)d_in[13];
  const float *g1=(const float*)d_in[14], *be1=(const float*)d_in[15];
  const float *g2=(const float*)d_in[16], *be2=(const float*)d_in[17];
  const float *g3=(const float*)d_in[18], *be3=(const float*)d_in[19];
  const float *Wm0=(const float*)d_in[20], *gm0=(const float*)d_in[21], *bem0=(const float*)d_in[22];
  const float *Wm1=(const float*)d_in[23], *gm1=(const float*)d_in[24], *bem1=(const float*)d_in[25];
  const float *Wm2=(const float*)d_in[26], *bm2=(const float*)d_in[27];
  float* out = (float*)d_out;

  char* ws = (char*)d_ws;
  int*   cnt     = (int*)(ws);
  int*   row_ptr = (int*)(ws + (1ull<<20));
  int*   cursor  = (int*)(ws + (2ull<<20));
  int*   pre     = (int*)(ws + (3ull<<20));
  int*   blksum  = (int*)(ws + (4ull<<20));
  float* invdeg  = (float*)(ws + (5ull<<20));
  int*   adj     = (int*)(ws + (6ull<<20));                 // 4.8 MB
  float* agg14   = (float*)(ws + (12ull<<20));              // 6.7 MB fp32
  unsigned short* aggm = (unsigned short*)(ws + (20ull<<20)); // 15.4 MB bf16
  unsigned short* hA   = (unsigned short*)(ws + (40ull<<20)); // 15.4 MB bf16
  unsigned short* hB   = (unsigned short*)(ws + (60ull<<20)); // 15.4 MB bf16
  float* stats   = (float*)(ws + (80ull<<20));              // 5 x 128
  float* wbuf    = (float*)(ws + (80ull<<20) + 4096);       // conv1 fp32 fold
  unsigned short* fragC = (unsigned short*)(ws + (81ull<<20)); // 16 KB
  float* bias2C  = (float*)(ws + (81ull<<20) + 65536);
  unsigned short* fragL = (unsigned short*)(ws + (82ull<<20)); // 8 KB
  float* bias2L  = (float*)(ws + (82ull<<20) + 65536);

  hipMemsetAsync(cnt, 0, NN*sizeof(int), stream);
  hipMemsetAsync(stats, 0, 5*128*sizeof(float), stream);
  k_count<<<(EE+255)/256,256,0,stream>>>(dstp, cnt);
  k_scan1<<<NB_SCAN,256,0,stream>>>(cnt, pre, blksum);
  k_scan2<<<1,512,0,stream>>>(blksum);
  k_scan3<<<NB_SCAN,256,0,stream>>>(pre, blksum, cnt, row_ptr, cursor, invdeg);
  k_fill<<<(EE+255)/256,256,0,stream>>>(srcp, dstp, cursor, adj);

  // conv1 (din=14, lrelu) scalar path -> hA(bf16); stats S1
  k_gather14<<<2048,256,0,stream>>>(x1, row_ptr, cnt, adj, agg14);
  k_prep<<<1,256,0,stream>>>(Wn1,Wr1,b1,nullptr,nullptr,nullptr,wbuf,14);
  k_gemm_conv14<<<NCBLK,128,0,stream>>>(agg14,x1,invdeg,wbuf,hA);
  k_stats<<<512,256,0,stream>>>(hA, stats);

  // conv2 (BN1 folded, lrelu) -> hB; stats S2
  k_gather64b<<<2048,256,0,stream>>>(hA, row_ptr, cnt, adj, invdeg, aggm);
  k_prep_conv_frag<<<1,256,0,stream>>>(Wn2,Wr2,b2,stats,g1,be1,fragC,bias2C);
  k_mfma<true,1><<<NMFMABLK,256,0,stream>>>(aggm,hA,invdeg,fragC,bias2C,hB);
  k_stats<<<512,256,0,stream>>>(hB, stats+128);

  // conv3 (BN2 folded, relu) -> hA; stats S3
  k_gather64b<<<2048,256,0,stream>>>(hB, row_ptr, cnt, adj, invdeg, aggm);
  k_prep_conv_frag<<<1,256,0,stream>>>(Wn3,Wr3,b3,stats+128,g2,be2,fragC,bias2C);
  k_mfma<true,2><<<NMFMABLK,256,0,stream>>>(aggm,hB,invdeg,fragC,bias2C,hA);
  k_stats<<<512,256,0,stream>>>(hA, stats+256);

  // conv4 (BN3 folded, no act) -> hB
  k_gather64b<<<2048,256,0,stream>>>(hA, row_ptr, cnt, adj, invdeg, aggm);
  k_prep_conv_frag<<<1,256,0,stream>>>(Wn4,Wr4,b4,stats+256,g3,be3,fragC,bias2C);
  k_mfma<true,0><<<NMFMABLK,256,0,stream>>>(aggm,hA,invdeg,fragC,bias2C,hB);

  // MLP head
  k_prep_lin_frag<<<1,256,0,stream>>>(Wm0, fragL, bias2L);
  k_mfma<false,0><<<NMFMABLK,256,0,stream>>>(hB,hB,invdeg,fragL,bias2L,hA);
  k_stats<<<512,256,0,stream>>>(hA, stats+384);
  k_normrelu<<<(NN*64)/1024,256,0,stream>>>(hA,stats+384,gm0,bem0);

  k_prep_lin_frag<<<1,256,0,stream>>>(Wm1, fragL, bias2L);
  k_mfma<false,0><<<NMFMABLK,256,0,stream>>>(hA,hA,invdeg,fragL,bias2L,hB);
  k_stats<<<512,256,0,stream>>>(hB, stats+512);
  k_normrelu<<<(NN*64)/1024,256,0,stream>>>(hB,stats+512,gm1,bem1);

  k_lin21<<<NCBLK,128,0,stream>>>(hB,Wm2,bm2,out);
}